// Round 3
// baseline (482.435 us; speedup 1.0000x reference)
//
#include <hip/hip_runtime.h>
#include <cstdint>
#include <cstddef>

#define NROWS 131072
#define DDIM  1024
#define LDIM  128
#define BSEG  64

typedef float f32x4 __attribute__((ext_vector_type(4)));
typedef short short8 __attribute__((ext_vector_type(8)));

#define FIXSCALE 9007199254740992.0   // 2^53

__device__ inline unsigned short f2bf(float f) {
    union { float f; unsigned u; } x; x.f = f;
    unsigned u = x.u + 0x7fffu + ((x.u >> 16) & 1u);
    return (unsigned short)(u >> 16);
}

__device__ inline int lower_bound_dev(const int* __restrict__ arr, int n, int v) {
    int lo = 0, hi = n;
    while (lo < hi) { int mid = (lo + hi) >> 1; if (arr[mid] < v) lo = mid + 1; else hi = mid; }
    return lo;
}

// ---------------- W pre-convert: f32 -> bf16, fragment-major packed layout ----------------
// frag f = ((kt*2 + kk)*4 + wc)*4 + nf ; byte = f*1024 + lane*16 ; lane = kl*16 + rA
// lane chunk holds W[n = wc*64+nf*16+rA][k = kt*64+kk*32+kl*8 .. +8] as 8 bf16.
__global__ void wconv_kernel(const float* __restrict__ Wa, const float* __restrict__ Wb,
                             unsigned short* __restrict__ wpre) {
    int n  = blockIdx.x;                 // 0..255 (W row / output col)
    int kt = threadIdx.x >> 4;           // 0..15
    int q  = threadIdx.x & 15;           // k quad: k = kt*64 + q*4
    const float* wrow = (n < LDIM) ? (Wa + (size_t)n * DDIM)
                                   : (Wb + (size_t)(n - LDIM) * DDIM);
    float4 v = *(const float4*)(wrow + kt * 64 + q * 4);
    ushort4 h;
    h.x = f2bf(v.x); h.y = f2bf(v.y); h.z = f2bf(v.z); h.w = f2bf(v.w);
    int kk    = q >> 3;
    int rem   = (q & 7) * 4;             // element offset within kk-half: 0..28
    int kl    = rem >> 3;                // 0..3
    int inner = (rem & 7) * 2;           // 0 or 8 bytes
    int lane  = kl * 16 + (n & 15);
    int f     = ((kt * 2 + kk) * 4 + (n >> 6)) * 4 + ((n >> 4) & 3);
    *(ushort4*)((char*)wpre + f * 1024 + lane * 16 + inner) = h;
}

// ---------------- fused norm + GEMM + gated score ----------------
// BM=64 rows/block, 256 threads (4 waves). A: 16 KB double-buffered swizzled LDS.
// W: direct L2->VGPR coalesced fragment loads (no LDS, no barrier coupling).
__global__ __launch_bounds__(256, 3)
void gemm_kernel(const float* __restrict__ feat, const unsigned short* __restrict__ wpre,
                 const float* __restrict__ ba, const float* __restrict__ bb,
                 const float* __restrict__ Wc, const float* __restrict__ bc,
                 float* __restrict__ nf_out, float* __restrict__ s_out)
{
    __shared__ __align__(16) char smem[33792];   // A dbuf 16 KB; epilogue overlay 33792 B
    float* ab = (float*)smem;

    const int tid  = threadIdx.x;
    const int w    = tid >> 6;
    const int lane = tid & 63;
    const int rblk = blockIdx.x * 64;
    const int sr   = tid >> 2;     // staging row 0..63
    const int sc4  = tid & 3;      // staging col-quad 0..3

    const float4* rowp4 = (const float4*)(feat + (size_t)(rblk + sr) * DDIM);

    // ---- phase 0: row sum-of-squares (the one HBM read of feature)
    float a0 = 0.f, a1 = 0.f, a2 = 0.f, a3 = 0.f;
    for (int t = 0; t < 64; t += 4) {
        float4 va = rowp4[sc4 + 4 * t];
        float4 vb = rowp4[sc4 + 4 * t + 4];
        float4 vc = rowp4[sc4 + 4 * t + 8];
        float4 vd = rowp4[sc4 + 4 * t + 12];
        a0 += va.x * va.x + va.y * va.y + va.z * va.z + va.w * va.w;
        a1 += vb.x * vb.x + vb.y * vb.y + vb.z * vb.z + vb.w * vb.w;
        a2 += vc.x * vc.x + vc.y * vc.y + vc.z * vc.z + vc.w * vc.w;
        a3 += vd.x * vd.x + vd.y * vd.y + vd.z * vd.z + vd.w * vd.w;
    }
    float ss = a0 + a1 + a2 + a3;
    ss += __shfl_xor(ss, 1, 64);
    ss += __shfl_xor(ss, 2, 64);
    const float invA = 1.f / fmaxf(sqrtf(ss), 1e-12f);

    f32x4 acc[4][4];
    #pragma unroll
    for (int i = 0; i < 4; ++i)
        #pragma unroll
        for (int j = 0; j < 4; ++j)
            acc[i][j] = (f32x4){0.f, 0.f, 0.f, 0.f};

    const int rA  = lane & 15;
    const int kl  = lane >> 4;
    const int swz = (lane & 7) << 4;
    const char* wsrc = (const char*)wpre + w * 4096 + lane * 16;

    // ---- prologue: stage A tile kt=0 into buffer 0 (normalize + nf store + bf16 LDS)
    #pragma unroll
    for (int j = 0; j < 4; ++j) {
        int cf = sc4 + j * 4;
        float4 v = rowp4[cf];
        v.x *= invA; v.y *= invA; v.z *= invA; v.w *= invA;
        *(float4*)(nf_out + (size_t)(rblk + sr) * DDIM + cf * 4) = v;
        ushort4 h;
        h.x = f2bf(v.x); h.y = f2bf(v.y); h.z = f2bf(v.z); h.w = f2bf(v.w);
        *(ushort4*)(smem + ((sr * 128 + cf * 8) ^ ((sr & 7) << 4))) = h;
    }
    __syncthreads();

    int cur = 0;
    for (int kt = 0; kt < 16; ++kt) {
        // W fragments for this tile: 8 coalesced 1-KB wave loads from L2-resident wpre
        short8 wf[8];
        #pragma unroll
        for (int q = 0; q < 8; ++q) {
            int kk = q >> 2, nf = q & 3;
            wf[q] = *(const short8*)(wsrc + (size_t)kt * 32768 + kk * 16384 + nf * 1024);
        }
        // next A tile f32 loads (L2-warm), issued early
        float4 av[4];
        if (kt < 15) {
            #pragma unroll
            for (int j = 0; j < 4; ++j)
                av[j] = rowp4[(kt + 1) * 16 + sc4 + j * 4];
        }

        // compute on current A buffer
        {
            const char* Abuf = smem + cur * 8192;
            #pragma unroll
            for (int kk = 0; kk < 2; ++kk) {
                int koff = (kk * 64 + kl * 16) ^ swz;
                #pragma unroll
                for (int mf = 0; mf < 4; ++mf) {
                    short8 af = *(const short8*)(Abuf + (mf * 16 + rA) * 128 + koff);
                    #pragma unroll
                    for (int nf = 0; nf < 4; ++nf)
                        acc[mf][nf] = __builtin_amdgcn_mfma_f32_16x16x32_bf16(
                            af, wf[kk * 4 + nf], acc[mf][nf], 0, 0, 0);
                }
            }
        }

        if (kt < 15) {
            char* Abuf = smem + (cur ^ 1) * 8192;
            #pragma unroll
            for (int j = 0; j < 4; ++j) {
                int cf = sc4 + j * 4;
                float4 v = av[j];
                v.x *= invA; v.y *= invA; v.z *= invA; v.w *= invA;
                *(float4*)(nf_out + (size_t)(rblk + sr) * DDIM + (kt + 1) * 64 + cf * 4) = v;
                ushort4 h;
                h.x = f2bf(v.x); h.y = f2bf(v.y); h.z = f2bf(v.z); h.w = f2bf(v.w);
                *(ushort4*)(Abuf + ((sr * 128 + cf * 8) ^ ((sr & 7) << 4))) = h;
            }
        }
        __syncthreads();
        cur ^= 1;
    }

    // ---- epilogue: a = sigmoid(.+ba) (waves 0,1); p = a * tanh(.+bb) (waves 2,3)
    const float bcv = bc[0];
    if (w < 2) {
        #pragma unroll
        for (int mf = 0; mf < 4; ++mf)
            #pragma unroll
            for (int nf = 0; nf < 4; ++nf) {
                int n = w * 64 + nf * 16 + rA;
                float bias = ba[n];
                #pragma unroll
                for (int reg = 0; reg < 4; ++reg) {
                    int r = mf * 16 + kl * 4 + reg;
                    float v = acc[mf][nf][reg] + bias;
                    ab[r * 132 + n] = 1.f / (1.f + __expf(-v));
                }
            }
    }
    __syncthreads();
    if (w >= 2) {
        #pragma unroll
        for (int mf = 0; mf < 4; ++mf)
            #pragma unroll
            for (int nf = 0; nf < 4; ++nf) {
                int l = (w - 2) * 64 + nf * 16 + rA;
                float bias = bb[l];
                #pragma unroll
                for (int reg = 0; reg < 4; ++reg) {
                    int r = mf * 16 + kl * 4 + reg;
                    float v = acc[mf][nf][reg] + bias;
                    ab[r * 132 + l] *= tanhf(v);
                }
            }
    }
    __syncthreads();
    // ---- reduce over L=128 with Wc; 4 threads per row
    {
        int rho = tid >> 2, q = tid & 3;
        float sum = 0.f;
        #pragma unroll
        for (int j = 0; j < 32; ++j) {
            int l = q + 4 * j;
            sum += ab[rho * 132 + l] * Wc[l];
        }
        sum += __shfl_xor(sum, 1, 64);
        sum += __shfl_xor(sum, 2, 64);
        if (q == 0) s_out[rblk + rho] = sum + bcv;
    }
}

// ---------------- softmax per segment, in place ----------------
__global__ void softmax_kernel(const int* __restrict__ batch, float* __restrict__ score) {
    int b = blockIdx.x;
    int tid = threadIdx.x;
    int start = lower_bound_dev(batch, NROWS, b);
    int end   = lower_bound_dev(batch, NROWS, b + 1);
    __shared__ float red[4];
    __shared__ float bm, bd;

    float m = -INFINITY;
    for (int i = start + tid; i < end; i += 256) m = fmaxf(m, score[i]);
    #pragma unroll
    for (int k = 1; k < 64; k <<= 1) m = fmaxf(m, __shfl_xor(m, k, 64));
    if ((tid & 63) == 0) red[tid >> 6] = m;
    __syncthreads();
    if (tid == 0) bm = fmaxf(fmaxf(red[0], red[1]), fmaxf(red[2], red[3]));
    __syncthreads();
    float M = bm;

    float sum = 0.f;
    for (int i = start + tid; i < end; i += 256) sum += __expf(score[i] - M);
    #pragma unroll
    for (int k = 1; k < 64; k <<= 1) sum += __shfl_xor(sum, k, 64);
    if ((tid & 63) == 0) red[tid >> 6] = sum;
    __syncthreads();
    if (tid == 0) bd = red[0] + red[1] + red[2] + red[3];
    __syncthreads();
    float invD = 1.f / bd;

    for (int i = start + tid; i < end; i += 256)
        score[i] = __expf(score[i] - M) * invD;
}

// ---------------- outsum: 16 row-slices/segment, int64 fixed-point atomics ----------------
__global__ void outsum1_kernel(const int* __restrict__ batch, const float* __restrict__ score,
                               const float* __restrict__ nf, unsigned long long* __restrict__ acc64) {
    int b  = blockIdx.x >> 4;
    int sl = blockIdx.x & 15;
    int t  = threadIdx.x;          // float4 column 0..255
    int start = lower_bound_dev(batch, NROWS, b);
    int end   = lower_bound_dev(batch, NROWS, b + 1);
    float4 a = {0.f, 0.f, 0.f, 0.f};
    for (int i = start + sl; i < end; i += 16) {
        float s = score[i];
        float4 v = *(const float4*)(nf + (size_t)i * DDIM + t * 4);
        a.x += s * v.x; a.y += s * v.y; a.z += s * v.z; a.w += s * v.w;
    }
    unsigned long long* dst = acc64 + (size_t)b * DDIM + t * 4;
    atomicAdd(&dst[0], (unsigned long long)(long long)((double)a.x * FIXSCALE));
    atomicAdd(&dst[1], (unsigned long long)(long long)((double)a.y * FIXSCALE));
    atomicAdd(&dst[2], (unsigned long long)(long long)((double)a.z * FIXSCALE));
    atomicAdd(&dst[3], (unsigned long long)(long long)((double)a.w * FIXSCALE));
}

__global__ void outsum2_kernel(const unsigned long long* __restrict__ acc64,
                               float* __restrict__ out) {
    int i = blockIdx.x * 256 + threadIdx.x;
    out[i] = (float)((double)(long long)acc64[i] * (1.0 / FIXSCALE));
}

extern "C" void kernel_launch(void* const* d_in, const int* in_sizes, int n_in,
                              void* d_out, int out_size, void* d_ws, size_t ws_size,
                              hipStream_t stream) {
    const float* feat  = (const float*)d_in[0];
    const int*   batch = (const int*)d_in[1];
    const float* Wa = (const float*)d_in[2];
    const float* ba = (const float*)d_in[3];
    const float* Wb = (const float*)d_in[4];
    const float* bb = (const float*)d_in[5];
    const float* Wc = (const float*)d_in[6];
    const float* bc = (const float*)d_in[7];

    float* out_seg = (float*)d_out;                  // B*D
    float* score   = out_seg + (size_t)BSEG * DDIM;  // N (s, then softmax in place)
    float* nf      = score + NROWS;                  // N*D

    unsigned short*     wpre  = (unsigned short*)d_ws;                       // 512 KB
    unsigned long long* acc64 = (unsigned long long*)((char*)d_ws + 524288); // 512 KB

    hipMemsetAsync(acc64, 0, (size_t)BSEG * DDIM * 8, stream);
    wconv_kernel<<<256, 256, 0, stream>>>(Wa, Wb, wpre);
    gemm_kernel<<<NROWS / 64, 256, 0, stream>>>(feat, wpre, ba, bb, Wc, bc, nf, score);
    softmax_kernel<<<BSEG, 256, 0, stream>>>(batch, score);
    outsum1_kernel<<<BSEG * 16, 256, 0, stream>>>(batch, score, nf, acc64);
    outsum2_kernel<<<BSEG * DDIM / 256, 256, 0, stream>>>(acc64, out_seg);
}

// Round 4
// 386.091 us; speedup vs baseline: 1.2495x; 1.2495x over previous
//
#include <hip/hip_runtime.h>
#include <cstdint>
#include <cstddef>

#define NROWS 131072
#define DDIM  1024
#define LDIM  128
#define BSEG  64
#define FIX2  281474976710656.0   // 2^48

typedef float f32x4 __attribute__((ext_vector_type(4)));
typedef short short8 __attribute__((ext_vector_type(8)));

__device__ inline unsigned short f2bf(float f) {
    union { float f; unsigned u; } x; x.f = f;
    unsigned u = x.u + 0x7fffu + ((x.u >> 16) & 1u);
    return (unsigned short)(u >> 16);
}

__device__ inline int lower_bound_dev(const int* __restrict__ arr, int n, int v) {
    int lo = 0, hi = n;
    while (lo < hi) { int mid = (lo + hi) >> 1; if (arr[mid] < v) lo = mid + 1; else hi = mid; }
    return lo;
}

// ---------------- W pre-convert: f32 -> bf16, fragment-major packed layout ----------------
// Wave w owns cols: nfi 0,1 -> Wa rows w*32+{0,16}+rA ; nfi 2,3 -> Wb rows w*32+{0,16}+rA.
// frag f = ((kt*2+kk)*4 + w)*4 + nfi ; byte = f*1024 + lane*16 + inner ; lane = kl*16 + rA.
__global__ void wconv_kernel(const float* __restrict__ Wa, const float* __restrict__ Wb,
                             unsigned short* __restrict__ wpre) {
    int n  = blockIdx.x;                 // 0..255 (0..127 Wa, 128..255 Wb)
    int kt = threadIdx.x >> 4;           // 0..15
    int q  = threadIdx.x & 15;           // k quad: k = kt*64 + q*4
    const float* wrow = (n < LDIM) ? (Wa + (size_t)n * DDIM)
                                   : (Wb + (size_t)(n - LDIM) * DDIM);
    float4 v = *(const float4*)(wrow + kt * 64 + q * 4);
    ushort4 h;
    h.x = f2bf(v.x); h.y = f2bf(v.y); h.z = f2bf(v.z); h.w = f2bf(v.w);
    int w, nfi, rA;
    if (n < LDIM) { w = n >> 5; nfi = (n >> 4) & 1; rA = n & 15; }
    else { int m = n - LDIM; w = m >> 5; nfi = 2 + ((m >> 4) & 1); rA = m & 15; }
    int kk    = q >> 3;
    int e     = (q & 7) * 4;             // elem offset within kk-half (0..28)
    int kl    = e >> 3;
    int inner = (e & 7) * 2;             // byte offset within lane chunk
    int lane  = kl * 16 + rA;
    int f     = ((kt * 2 + kk) * 4 + w) * 4 + nfi;
    *(ushort4*)((char*)wpre + f * 1024 + lane * 16 + inner) = h;
}

// ---------------- fused GEMM (raw x) + post-norm + gated score + segment partial sums ----------------
__global__ __launch_bounds__(256, 4)
void gemm_kernel(const float* __restrict__ feat, const unsigned short* __restrict__ wpre,
                 const float* __restrict__ ba, const float* __restrict__ bb,
                 const float* __restrict__ Wc, const float* __restrict__ bc,
                 const int* __restrict__ batch,
                 float* __restrict__ nf_out, float* __restrict__ s_out,
                 unsigned long long* __restrict__ acc64)
{
    __shared__ __align__(16) char smem[18432];
    float* invA_l = (float*)(smem + 16384);   // [64]
    float* part   = (float*)(smem + 16640);   // [4][64]
    float* s_row  = (float*)(smem + 17664);   // [64]
    float* u_row  = (float*)(smem + 17920);   // [64]
    int*   seg_l  = (int*)(smem + 18176);     // [64]

    const int tid  = threadIdx.x;
    const int w    = tid >> 6;
    const int lane = tid & 63;
    const int rblk = blockIdx.x * 64;
    const int sr   = tid >> 2;     // staging row 0..63
    const int sc4  = tid & 3;      // staging col-quad 0..3

    if (tid < 64) seg_l[tid] = batch[rblk + tid];

    const float4* rowp4 = (const float4*)(feat + (size_t)(rblk + sr) * DDIM);

    f32x4 acc[4][4];
    #pragma unroll
    for (int i = 0; i < 4; ++i)
        #pragma unroll
        for (int j = 0; j < 4; ++j)
            acc[i][j] = (f32x4){0.f, 0.f, 0.f, 0.f};

    const int rA  = lane & 15;
    const int kl  = lane >> 4;
    const int swz = (lane & 7) << 4;
    const char* wsrc = (const char*)wpre + w * 4096 + lane * 16;

    float sq = 0.f;

    // ---- prologue: stage raw tile kt=0 (convert + accumulate squares)
    #pragma unroll
    for (int j = 0; j < 4; ++j) {
        int cf = sc4 + j * 4;
        float4 v = rowp4[cf];
        sq += v.x * v.x + v.y * v.y + v.z * v.z + v.w * v.w;
        ushort4 h;
        h.x = f2bf(v.x); h.y = f2bf(v.y); h.z = f2bf(v.z); h.w = f2bf(v.w);
        *(ushort4*)(smem + ((sr * 128 + cf * 8) ^ ((sr & 7) << 4))) = h;
    }
    __syncthreads();

    int cur = 0;
    for (int kt = 0; kt < 16; ++kt) {
        // next raw A tile: HBM loads issued first (longest latency)
        float4 av[4];
        if (kt < 15) {
            #pragma unroll
            for (int j = 0; j < 4; ++j)
                av[j] = rowp4[(kt + 1) * 16 + sc4 + j * 4];
        }
        // W fragments for this tile: 8 coalesced 1-KB wave loads (L2-resident)
        short8 wf[8];
        #pragma unroll
        for (int q = 0; q < 8; ++q) {
            int kk = q >> 2, nfi = q & 3;
            wf[q] = *(const short8*)(wsrc + (size_t)kt * 32768 + kk * 16384 + nfi * 1024);
        }
        // compute on current A buffer
        {
            const char* Abuf = smem + cur * 8192;
            #pragma unroll
            for (int kk = 0; kk < 2; ++kk) {
                int koff = (kk * 64 + kl * 16) ^ swz;
                #pragma unroll
                for (int mf = 0; mf < 4; ++mf) {
                    short8 af = *(const short8*)(Abuf + (mf * 16 + rA) * 128 + koff);
                    #pragma unroll
                    for (int nfi = 0; nfi < 4; ++nfi)
                        acc[mf][nfi] = __builtin_amdgcn_mfma_f32_16x16x32_bf16(
                            af, wf[kk * 4 + nfi], acc[mf][nfi], 0, 0, 0);
                }
            }
        }
        // stage next tile into alternate buffer
        if (kt < 15) {
            char* Abuf = smem + (cur ^ 1) * 8192;
            #pragma unroll
            for (int j = 0; j < 4; ++j) {
                int cf = sc4 + j * 4;
                float4 v = av[j];
                sq += v.x * v.x + v.y * v.y + v.z * v.z + v.w * v.w;
                ushort4 h;
                h.x = f2bf(v.x); h.y = f2bf(v.y); h.z = f2bf(v.z); h.w = f2bf(v.w);
                *(ushort4*)(Abuf + ((sr * 128 + cf * 8) ^ ((sr & 7) << 4))) = h;
            }
        }
        __syncthreads();
        cur ^= 1;
    }

    // ---- finalize invA (4 staging threads per row hold partials)
    sq += __shfl_xor(sq, 1, 64);
    sq += __shfl_xor(sq, 2, 64);
    if (sc4 == 0) invA_l[sr] = 1.f / fmaxf(sqrtf(sq), 1e-12f);
    __syncthreads();

    // ---- epilogue-1: gated score, all lane-local (wave owns matching Wa/Wb cols)
    {
        int l0 = w * 32 + rA, l1 = l0 + 16;
        float ba0 = ba[l0], ba1 = ba[l1], bb0 = bb[l0], bb1 = bb[l1];
        float wc0 = Wc[l0], wc1 = Wc[l1];
        float vals[4][4];
        #pragma unroll
        for (int mf = 0; mf < 4; ++mf)
            #pragma unroll
            for (int reg = 0; reg < 4; ++reg) {
                int r = mf * 16 + kl * 4 + reg;
                float ia = invA_l[r];
                float pa0 = acc[mf][0][reg] * ia + ba0;
                float pb0 = acc[mf][2][reg] * ia + bb0;
                float pa1 = acc[mf][1][reg] * ia + ba1;
                float pb1 = acc[mf][3][reg] * ia + bb1;
                float a0 = 1.f / (1.f + __expf(-pa0));
                float b0 = 1.f - 2.f / (1.f + __expf(2.f * pb0));
                float a1 = 1.f / (1.f + __expf(-pa1));
                float b1 = 1.f - 2.f / (1.f + __expf(2.f * pb1));
                vals[mf][reg] = a0 * b0 * wc0 + a1 * b1 * wc1;
            }
        #pragma unroll
        for (int mf = 0; mf < 4; ++mf)
            #pragma unroll
            for (int reg = 0; reg < 4; ++reg) {
                float v = vals[mf][reg];
                v += __shfl_xor(v, 1, 64);
                v += __shfl_xor(v, 2, 64);
                v += __shfl_xor(v, 4, 64);
                v += __shfl_xor(v, 8, 64);
                vals[mf][reg] = v;
            }
        if (rA == 0) {
            #pragma unroll
            for (int mf = 0; mf < 4; ++mf)
                #pragma unroll
                for (int reg = 0; reg < 4; ++reg)
                    part[w * 64 + mf * 16 + kl * 4 + reg] = vals[mf][reg];
        }
    }
    __syncthreads();
    if (tid < 64) {
        float s = part[tid] + part[64 + tid] + part[128 + tid] + part[192 + tid] + bc[0];
        s_row[tid] = s;
        u_row[tid] = __expf(s);
        s_out[rblk + tid] = s;
    }
    __syncthreads();

    // ---- epilogue-2: nf write (x*invA) + per-segment weighted partials (fixed-point atomics)
    {
        const float4* fbase = (const float4*)(feat + (size_t)rblk * DDIM);
        float4*       nbase = (float4*)(nf_out + (size_t)rblk * DDIM);
        float ax = 0.f, ay = 0.f, az = 0.f, aw = 0.f;
        int curseg = seg_l[0];
        for (int r = 0; r < 64; ++r) {
            int sg = seg_l[r];
            if (sg != curseg) {
                unsigned long long* dst = acc64 + (size_t)curseg * DDIM + tid * 4;
                atomicAdd(&dst[0], (unsigned long long)(long long)((double)ax * FIX2));
                atomicAdd(&dst[1], (unsigned long long)(long long)((double)ay * FIX2));
                atomicAdd(&dst[2], (unsigned long long)(long long)((double)az * FIX2));
                atomicAdd(&dst[3], (unsigned long long)(long long)((double)aw * FIX2));
                ax = ay = az = aw = 0.f;
                curseg = sg;
            }
            float ia = invA_l[r];
            float u  = u_row[r];
            float4 v = fbase[r * 256 + tid];
            v.x *= ia; v.y *= ia; v.z *= ia; v.w *= ia;
            nbase[r * 256 + tid] = v;
            ax += u * v.x; ay += u * v.y; az += u * v.z; aw += u * v.w;
        }
        unsigned long long* dst = acc64 + (size_t)curseg * DDIM + tid * 4;
        atomicAdd(&dst[0], (unsigned long long)(long long)((double)ax * FIX2));
        atomicAdd(&dst[1], (unsigned long long)(long long)((double)ay * FIX2));
        atomicAdd(&dst[2], (unsigned long long)(long long)((double)az * FIX2));
        atomicAdd(&dst[3], (unsigned long long)(long long)((double)aw * FIX2));
    }
}

// ---------------- softmax per segment, in place; also emits per-segment M and D ----------------
__global__ void softmax_kernel(const int* __restrict__ batch, float* __restrict__ score,
                               float* __restrict__ smax, float* __restrict__ ssum) {
    int b = blockIdx.x;
    int tid = threadIdx.x;
    int start = lower_bound_dev(batch, NROWS, b);
    int end   = lower_bound_dev(batch, NROWS, b + 1);
    __shared__ float red[4];
    __shared__ float bm, bd;

    float m = -INFINITY;
    for (int i = start + tid; i < end; i += 256) m = fmaxf(m, score[i]);
    #pragma unroll
    for (int k = 1; k < 64; k <<= 1) m = fmaxf(m, __shfl_xor(m, k, 64));
    if ((tid & 63) == 0) red[tid >> 6] = m;
    __syncthreads();
    if (tid == 0) bm = fmaxf(fmaxf(red[0], red[1]), fmaxf(red[2], red[3]));
    __syncthreads();
    float M = bm;

    float sum = 0.f;
    for (int i = start + tid; i < end; i += 256) sum += __expf(score[i] - M);
    #pragma unroll
    for (int k = 1; k < 64; k <<= 1) sum += __shfl_xor(sum, k, 64);
    if ((tid & 63) == 0) red[tid >> 6] = sum;
    __syncthreads();
    if (tid == 0) { bd = red[0] + red[1] + red[2] + red[3]; smax[b] = bm; ssum[b] = bd; }
    __syncthreads();
    float invD = 1.f / bd;

    for (int i = start + tid; i < end; i += 256)
        score[i] = __expf(score[i] - M) * invD;
}

// ---------------- finalize: out = fix2float(acc64) / (e^M * D) ----------------
__global__ void finalize_kernel(const unsigned long long* __restrict__ acc64,
                                const float* __restrict__ smax, const float* __restrict__ ssum,
                                float* __restrict__ out) {
    int i = blockIdx.x * 256 + threadIdx.x;
    int b = i >> 10;
    double denom = exp((double)smax[b]) * (double)ssum[b];
    out[i] = (float)(((double)(long long)acc64[i]) * (1.0 / FIX2) / denom);
}

extern "C" void kernel_launch(void* const* d_in, const int* in_sizes, int n_in,
                              void* d_out, int out_size, void* d_ws, size_t ws_size,
                              hipStream_t stream) {
    const float* feat  = (const float*)d_in[0];
    const int*   batch = (const int*)d_in[1];
    const float* Wa = (const float*)d_in[2];
    const float* ba = (const float*)d_in[3];
    const float* Wb = (const float*)d_in[4];
    const float* bb = (const float*)d_in[5];
    const float* Wc = (const float*)d_in[6];
    const float* bc = (const float*)d_in[7];

    float* out_seg = (float*)d_out;                  // B*D
    float* score   = out_seg + (size_t)BSEG * DDIM;  // N (raw s, then softmax in place)
    float* nf      = score + NROWS;                  // N*D

    unsigned short*     wpre  = (unsigned short*)d_ws;                       // 512 KB
    unsigned long long* acc64 = (unsigned long long*)((char*)d_ws + 524288); // 512 KB
    // smax/ssum overlay the wpre region: written after gemm is done with wpre
    float* smax = (float*)d_ws;
    float* ssum = smax + BSEG;

    hipMemsetAsync(acc64, 0, (size_t)BSEG * DDIM * 8, stream);
    wconv_kernel<<<256, 256, 0, stream>>>(Wa, Wb, wpre);
    gemm_kernel<<<NROWS / 64, 256, 0, stream>>>(feat, wpre, ba, bb, Wc, bc, batch,
                                                nf, score, acc64);
    softmax_kernel<<<BSEG, 256, 0, stream>>>(batch, score, smax, ssum);
    finalize_kernel<<<BSEG * DDIM / 256, 256, 0, stream>>>(acc64, smax, ssum, out_seg);
}